// Round 1
// 288.060 us; speedup vs baseline: 1.1007x; 1.1007x over previous
//
#include <hip/hip_runtime.h>
#include <hip/hip_bf16.h>
#include <stdint.h>

#define DIM 512
#define NROWS 1024
#define NCLS 70722
#define NCTILE 553     // ceil(70722/128)

typedef float floatx4 __attribute__((ext_vector_type(4)));

// pack 4 floats -> 4 OCP e4m3 bytes (HW cvt, RNE+sat)
__device__ __forceinline__ unsigned pk4_fp8(float a, float b, float c, float d) {
    unsigned v = 0;
    v = __builtin_amdgcn_cvt_pk_fp8_f32(a, b, v, false);  // low 16 bits
    v = __builtin_amdgcn_cvt_pk_fp8_f32(c, d, v, true);   // high 16 bits
    return v;
}

__device__ __forceinline__ float wave_reduce_sum(float s) {
    #pragma unroll
    for (int m = 1; m < 64; m <<= 1) s += __shfl_xor(s, m);
    return s;
}

// --- kernel 1: fused prep ---------------------------------------------------
// blocks [0,256):    x rows -> fp8(16*x/||x||), rownorm, fp32 label cosine, rowsum=0
// blocks [256,...):  W rows -> fp8(16*w/||w||), wave-per-row fully coalesced
__global__ __launch_bounds__(256) void prep_kernel(
        const float* __restrict__ x, const float* __restrict__ W,
        const int* __restrict__ labels,
        uint8_t* __restrict__ An, uint8_t* __restrict__ Wn8,
        float* __restrict__ rownorm, float* __restrict__ coslab,
        float* __restrict__ rowsum) {
    int b = blockIdx.x;
    int wv = threadIdx.x >> 6, lane = threadIdx.x & 63;
    if (b < NROWS / 4) {
        if (threadIdx.x < 4) rowsum[b * 4 + threadIdx.x] = 0.0f;
        int row = b * 4 + wv;
        int lab = labels[row];
        // lane covers 8 contiguous elements
        const float4* xs = (const float4*)(x + (size_t)row * DIM);
        const float4* ws = (const float4*)(W + (size_t)lab * DIM);
        float4 xa = xs[lane * 2], xb = xs[lane * 2 + 1];
        float4 wa = ws[lane * 2], wb = ws[lane * 2 + 1];
        float dxx = xa.x*xa.x + xa.y*xa.y + xa.z*xa.z + xa.w*xa.w
                  + xb.x*xb.x + xb.y*xb.y + xb.z*xb.z + xb.w*xb.w;
        float dww = wa.x*wa.x + wa.y*wa.y + wa.z*wa.z + wa.w*wa.w
                  + wb.x*wb.x + wb.y*wb.y + wb.z*wb.z + wb.w*wb.w;
        float dxw = xa.x*wa.x + xa.y*wa.y + xa.z*wa.z + xa.w*wa.w
                  + xb.x*wb.x + xb.y*wb.y + xb.z*wb.z + xb.w*wb.w;
        dxx = wave_reduce_sum(dxx);
        dww = wave_reduce_sum(dww);
        dxw = wave_reduce_sum(dxw);
        float norm = sqrtf(dxx);
        float s16 = 16.0f / fmaxf(norm, 1e-12f);
        uint2 p;
        p.x = pk4_fp8(xa.x*s16, xa.y*s16, xa.z*s16, xa.w*s16);
        p.y = pk4_fp8(xb.x*s16, xb.y*s16, xb.z*s16, xb.w*s16);
        *(uint2*)(An + (size_t)row * DIM + lane * 8) = p;
        if (lane == 0) {
            rownorm[row] = norm;
            coslab[row]  = dxw / (fmaxf(norm, 1e-12f) * fmaxf(sqrtf(dww), 1e-12f));
        }
    } else {
        // wave-per-row: 64 lanes x 32B contiguous load, 512B contiguous store
        int c = (b - NROWS / 4) * 4 + wv;
        if (c < NCLS) {
            const float4* src = (const float4*)(W + (size_t)c * DIM);
            float4 va = src[lane * 2], vb = src[lane * 2 + 1];
            float ss = va.x*va.x + va.y*va.y + va.z*va.z + va.w*va.w
                     + vb.x*vb.x + vb.y*vb.y + vb.z*vb.z + vb.w*vb.w;
            ss = wave_reduce_sum(ss);
            float s16 = 16.0f / fmaxf(sqrtf(ss), 1e-12f);
            uint2 p;
            p.x = pk4_fp8(va.x*s16, va.y*s16, va.z*s16, va.w*s16);
            p.y = pk4_fp8(vb.x*s16, vb.y*s16, vb.z*s16, vb.w*s16);
            *(uint2*)(Wn8 + (size_t)c * DIM + lane * 8) = p;
        }
    }
}

// --- kernel 2: fp8 128x128 GEMM, BK=64, dbuf LDS + counted vmcnt + sumexp ---
// LDS row = 64 fp8 = 4 x 16B chunks; physical chunk p of row r holds logical
// chunk p ^ g(r), g(r) = (r&3)^((r>>2)&3)  -> max 2-way bank conflict (free).
// (swizzle legal: global_load_lds source addr is per-lane, dest wave-uniform
//  + lane*16, so the involution is applied to the per-lane GLOBAL source.)
// 2-phase pipeline: stage tile k+1 into buf^1 while computing buf k;
// s_waitcnt vmcnt(4) keeps the 4 prefetch loads in flight across the barrier.
// acc * 2^-8 = cosine (inputs pre-scaled by 16).
// XCD swizzle: blocks sharing b%8 share ctile%8 -> same XCD L2 reuse of B.
__global__ __launch_bounds__(256) void gemm5_kernel(
        const uint8_t* __restrict__ An, const uint8_t* __restrict__ Wn8,
        float* __restrict__ rowsum) {
    __shared__ uint8_t As[2][128 * 64];   // 2 x 8 KB
    __shared__ uint8_t Bs[2][128 * 64];   // 2 x 8 KB
    __shared__ float red[128];
    int b = blockIdx.x;
    int ctile = (b >> 6) * 8 + (b & 7);
    int mtile = (b >> 3) & 7;
    if (ctile >= NCTILE) return;
    int t = threadIdx.x, lane = t & 63, wv = t >> 6;
    if (t < 128) red[t] = 0.0f;

    // staging: wave covers 16 rows x 64 B; lane -> row sr=lane>>2, phys chunk lane&3
    int sr = lane >> 2;
    int gs = (sr & 3) ^ ((sr >> 2) & 3);
    int ck = (((lane & 3) ^ gs) * 16);        // swizzled source chunk offset
    const uint8_t* aG = An + (size_t)(mtile * 128 + wv * 16 + sr) * DIM + ck;
    int c0 = min(ctile * 128 + wv * 16 + sr,      NCLS - 1);
    int c1 = min(ctile * 128 + 64 + wv * 16 + sr, NCLS - 1);
    const uint8_t* bG0 = Wn8 + (size_t)c0 * DIM + ck;
    const uint8_t* bG1 = Wn8 + (size_t)c1 * DIM + ck;
    int wvoff = wv * 16 * 64;                 // wave-uniform LDS base offset

    int wm = (wv >> 1) * 64, wn = (wv & 1) * 64;
    int fr = lane & 15, fq = lane >> 4;
    int fh = fq >> 1, fl = (fq & 1) * 8;      // chunk-half / 8B sub-slot

    floatx4 acc[4][4] = {};

#define GLL(gptr, lptr) __builtin_amdgcn_global_load_lds( \
        (const __attribute__((address_space(1))) unsigned int*)(gptr), \
        (__attribute__((address_space(3))) unsigned int*)(lptr), 16, 0, 0)

#define STAGE(buf, kc) do { \
        GLL(aG + (kc),                      As[buf] + wvoff); \
        GLL(aG + 64 * DIM + (kc),           As[buf] + wvoff + 64 * 64); \
        GLL(bG0 + (kc),                     Bs[buf] + wvoff); \
        GLL(bG1 + (kc),                     Bs[buf] + wvoff + 64 * 64); \
    } while (0)

#define COMPUTE_TILE(Ab, Bb) do { \
        long af[2][4], bf[2][4]; \
        _Pragma("unroll") \
        for (int mt = 0; mt < 4; ++mt) { \
            int R = wm + mt * 16 + fr; \
            int gRB = ((R & 3) ^ ((R >> 2) & 3)) * 16; \
            const uint8_t* rp = (Ab) + R * 64; \
            af[0][mt] = *(const long*)(rp + ((fh * 16) ^ gRB) + fl); \
            af[1][mt] = *(const long*)(rp + (((2 + fh) * 16) ^ gRB) + fl); \
        } \
        _Pragma("unroll") \
        for (int nt = 0; nt < 4; ++nt) { \
            int R = wn + nt * 16 + fr; \
            int gRB = ((R & 3) ^ ((R >> 2) & 3)) * 16; \
            const uint8_t* rp = (Bb) + R * 64; \
            bf[0][nt] = *(const long*)(rp + ((fh * 16) ^ gRB) + fl); \
            bf[1][nt] = *(const long*)(rp + (((2 + fh) * 16) ^ gRB) + fl); \
        } \
        _Pragma("unroll") \
        for (int s = 0; s < 2; ++s) \
            _Pragma("unroll") \
            for (int mt = 0; mt < 4; ++mt) \
                _Pragma("unroll") \
                for (int nt = 0; nt < 4; ++nt) \
                    acc[mt][nt] = __builtin_amdgcn_mfma_f32_16x16x32_fp8_fp8( \
                        af[s][mt], bf[s][nt], acc[mt][nt], 0, 0, 0); \
    } while (0)

    STAGE(0, 0);
    #pragma unroll
    for (int k = 0; k < 7; ++k) {
        STAGE((k + 1) & 1, (k + 1) * 64);     // prefetch next tile
        asm volatile("s_waitcnt vmcnt(4)" ::: "memory");  // current tile landed
        __builtin_amdgcn_s_barrier();
        COMPUTE_TILE(As[k & 1], Bs[k & 1]);
        asm volatile("" ::: "memory");        // pin LDS reads inside barrier pair
        __builtin_amdgcn_s_barrier();         // reads done before buf overwrite
    }
    asm volatile("s_waitcnt vmcnt(0)" ::: "memory");
    __builtin_amdgcn_s_barrier();
    COMPUTE_TILE(As[1], Bs[1]);               // k = 7 -> buffer 1

#undef GLL
#undef STAGE
#undef COMPUTE_TILE

    // epilogue: cosine = acc/256; exp(64c - 64); reduce per row
    const float CLIPC = 0.99999950f;  // cos(0.001)
    const float ISCL  = 1.0f / 256.0f;
    int colbase = ctile * 128 + wn + fr;
    #pragma unroll
    for (int mt = 0; mt < 4; ++mt) {
        #pragma unroll
        for (int reg = 0; reg < 4; ++reg) {
            float s = 0.0f;
            #pragma unroll
            for (int nt = 0; nt < 4; ++nt) {
                int col = colbase + nt * 16;
                float c = acc[mt][nt][reg] * ISCL;
                c = fminf(fmaxf(c, -CLIPC), CLIPC);
                float term = __expf(64.0f * c - 64.0f);
                s += (col < NCLS) ? term : 0.0f;
            }
            s += __shfl_xor(s, 1); s += __shfl_xor(s, 2);
            s += __shfl_xor(s, 4); s += __shfl_xor(s, 8);
            if (fr == 0) atomicAdd(&red[wm + mt * 16 + fq * 4 + reg], s);
        }
    }
    __syncthreads();
    if (t < 128) atomicAdd(rowsum + mtile * 128 + t, red[t]);
}

// --- kernel 3: fused batch-stats + margin correction + log + mean ----------
__global__ __launch_bounds__(1024) void finalize_kernel(
        const float* __restrict__ rowsum, const float* __restrict__ coslab,
        const float* __restrict__ rownorm, float* __restrict__ out) {
    __shared__ float sd[1024];
    int t = threadIdx.x;
    float v = fminf(fmaxf(rownorm[t], 0.001f), 100.0f);   // safe_norms
    sd[t] = v; __syncthreads();
    for (int s = 512; s > 0; s >>= 1) { if (t < s) sd[t] += sd[t + s]; __syncthreads(); }
    float mean = sd[0] * (1.0f / 1024.0f);
    __syncthreads();
    float d = v - mean;
    sd[t] = d * d; __syncthreads();
    for (int s = 512; s > 0; s >>= 1) { if (t < s) sd[t] += sd[t + s]; __syncthreads(); }
    float stdv = sqrtf(sd[0] * (1.0f / 1023.0f));         // ddof=1
    float ms = d / (stdv + 0.001f) * 0.333f;
    ms = fminf(fmaxf(ms, -1.0f), 1.0f);
    float g_ang = -0.4f * ms;
    float g_add =  0.4f + 0.4f * ms;
    const float CLIPC = 0.99999950f;
    const float PI = 3.14159265358979323846f;
    float cl  = fminf(fmaxf(coslab[t], -1.0f), 1.0f);
    float cne = fminf(fmaxf(cl, -CLIPC), CLIPC);
    float logit_non = 64.0f * cne;                        // ~ what the GEMM summed
    float theta = acosf(cl);
    float tm = fminf(fmaxf(theta + g_ang, 0.001f), PI - 0.001f);
    float logit_true = (__cosf(tm) - g_add) * 64.0f;
    float ssum = rowsum[t] - __expf(logit_non - 64.0f) + __expf(logit_true - 64.0f);
    float loss = logf(ssum) + 64.0f - logit_true;
    __syncthreads();
    sd[t] = loss; __syncthreads();
    for (int s = 512; s > 0; s >>= 1) { if (t < s) sd[t] += sd[t + s]; __syncthreads(); }
    if (t == 0) out[0] = sd[0] * (1.0f / 1024.0f);
}

extern "C" void kernel_launch(void* const* d_in, const int* in_sizes, int n_in,
                              void* d_out, int out_size, void* d_ws, size_t ws_size,
                              hipStream_t stream) {
    const float* x      = (const float*)d_in[0];
    const int*   labels = (const int*)d_in[1];
    const float* W      = (const float*)d_in[2];
    float* out = (float*)d_out;
    char* ws = (char*)d_ws;

    // workspace layout (~36.8 MB)
    const size_t SZ_WN8 = 36212736;   // 70722*512 fp8, 4K-aligned pad
    const size_t SZ_AN  = 524288;     // 1024*512 fp8
    uint8_t* Wn8 = (uint8_t*)ws;
    uint8_t* An  = (uint8_t*)(ws + SZ_WN8);
    float* rownorm = (float*)(ws + SZ_WN8 + SZ_AN);
    float* rowsum  = rownorm + 1024;
    float* coslab  = rowsum + 1024;

    int wblocks = (NCLS + 3) / 4;     // wave-per-row W normalization
    prep_kernel<<<NROWS / 4 + wblocks, 256, 0, stream>>>(
        x, W, labels, An, Wn8, rownorm, coslab, rowsum);
    gemm5_kernel<<<70 * 64, 256, 0, stream>>>(An, Wn8, rowsum);
    finalize_kernel<<<1, 1024, 0, stream>>>(rowsum, coslab, rownorm, out);
}